// Round 10
// baseline (186.481 us; speedup 1.0000x reference)
//
#include <hip/hip_runtime.h>

typedef _Float16 half8 __attribute__((ext_vector_type(8)));
typedef __fp16   fp16x2 __attribute__((ext_vector_type(2)));
typedef float    f32x4 __attribute__((ext_vector_type(4)));

#define DEV static __device__ __forceinline__

DEV unsigned short f2h(float f) {
  _Float16 h = (_Float16)f;
  return __builtin_bit_cast(unsigned short, h);
}
DEV float h2f(unsigned short u) { return (float)__builtin_bit_cast(_Float16, u); }
DEV float lrelu(float x) { return x > 0.f ? x : 0.01f * x; }
DEV f32x4 mfma16(half8 a, half8 b, f32x4 c) {
  return __builtin_amdgcn_mfma_f32_16x16x32_f16(a, b, c, 0, 0, 0);
}
DEV uint2 pk4(float4 v) {
  fp16x2 a = __builtin_amdgcn_cvt_pkrtz(v.x, v.y);
  fp16x2 b = __builtin_amdgcn_cvt_pkrtz(v.z, v.w);
  return make_uint2(__builtin_bit_cast(unsigned, a), __builtin_bit_cast(unsigned, b));
}

// dims: B=4 N=256 H=768 D=200 NH=5 HD=40 OUT=12
// Single launch: producers (blocks 0..379) + consumers (380..571) with
// device-scope flag. Epilogue algebra folded into main GEMM (Bt->P rows,
// A+biases+db->P col 200 with tail col200=1, E = only epilogue add).
#define N_PROD 380u

__global__ void __launch_bounds__(256) mega(
    const float* __restrict__ wr, const float* __restrict__ hw,
    const float* __restrict__ tw, const float* __restrict__ hb,
    const float* __restrict__ tb, const float* __restrict__ U,
    const float* __restrict__ W, const float* __restrict__ dw,
    const float* __restrict__ se, const float* __restrict__ db,
    unsigned short* __restrict__ headp, unsigned short* __restrict__ tail16,
    unsigned short* __restrict__ DWhp, unsigned short* __restrict__ DWtp,
    float* __restrict__ biasH, float* __restrict__ biasT,
    float* __restrict__ E, unsigned short* __restrict__ Gp,
    unsigned* __restrict__ flag, float* __restrict__ out)
{
  extern __shared__ __align__(16) char smem[];
  int bid = blockIdx.x, tid = threadIdx.x;
  int wid = tid >> 6, lane = tid & 63, r15 = lane & 15, g8 = lane >> 4;

  if (bid < (int)N_PROD) {
    if (bid < 56) {
      // ---- GEMM1: 128x64 tile, 4 waves (wave = 32-row strip)
      unsigned short* Xs  = (unsigned short*)smem;            // [128][136]
      unsigned short* Wsh = (unsigned short*)(smem + 34816);  // [64][136]
      int mt = bid / 7, nt = bid % 7;
      int rb = mt * 128, cb = nt * 64;
      int xrow = tid >> 1, xseg = tid & 1;
      int wrow = tid >> 2, wseg = tid & 3;
      int c = cb + wrow;
      f32x4 acc[2][4] = {};
      for (int kt = 0; kt < 6; ++kt) {
        int k0 = kt * 128;
        {
          const float4* s = reinterpret_cast<const float4*>(wr + (rb + xrow) * 768 + k0 + xseg * 64);
          uint4* d = reinterpret_cast<uint4*>(&Xs[xrow * 136 + xseg * 64]);
          #pragma unroll
          for (int j = 0; j < 8; ++j) {
            uint2 pa = pk4(s[2 * j]), pb = pk4(s[2 * j + 1]);
            d[j] = make_uint4(pa.x, pa.y, pb.x, pb.y);
          }
        }
        {
          uint4* d = reinterpret_cast<uint4*>(&Wsh[wrow * 136 + wseg * 32]);
          if (c < 400) {
            const float4* s = reinterpret_cast<const float4*>(
                (c < 200 ? hw + c * 768 : tw + (c - 200) * 768) + k0 + wseg * 32);
            #pragma unroll
            for (int j = 0; j < 4; ++j) {
              uint2 pa = pk4(s[2 * j]), pb = pk4(s[2 * j + 1]);
              d[j] = make_uint4(pa.x, pa.y, pb.x, pb.y);
            }
          } else {
            uint4 z = make_uint4(0u, 0u, 0u, 0u);
            #pragma unroll
            for (int j = 0; j < 4; ++j) d[j] = z;
          }
        }
        __syncthreads();
        #pragma unroll
        for (int ks = 0; ks < 4; ++ks) {
          half8 a[2], bb[4];
          #pragma unroll
          for (int g = 0; g < 2; ++g)
            a[g] = *reinterpret_cast<const half8*>(&Xs[(wid * 32 + g * 16 + r15) * 136 + ks * 32 + g8 * 8]);
          #pragma unroll
          for (int h = 0; h < 4; ++h)
            bb[h] = *reinterpret_cast<const half8*>(&Wsh[(h * 16 + r15) * 136 + ks * 32 + g8 * 8]);
          #pragma unroll
          for (int g = 0; g < 2; ++g) {
            #pragma unroll
            for (int h = 0; h < 4; ++h)
              acc[g][h] = mfma16(a[g], bb[h], acc[g][h]);
          }
        }
        __syncthreads();
      }
      #pragma unroll
      for (int h = 0; h < 4; ++h) {
        int cc = cb + h * 16 + r15;
        if (cc < 400) {
          float bias = (cc < 200) ? hb[cc] : tb[cc - 200];
          #pragma unroll
          for (int g = 0; g < 2; ++g) {
            #pragma unroll
            for (int q = 0; q < 4; ++q) {
              int m = rb + wid * 32 + g * 16 + g8 * 4 + q;
              float val = lrelu(acc[g][h][q] + bias);
              if (cc < 200) headp[m * 320 + (cc / 40) * 64 + (cc % 40)] = f2h(val);
              else          tail16[m * 224 + (cc - 200)] = f2h(val);
            }
          }
        }
      }
    } else if (bid < 157) {
      // ---- DW: wave-per-column (cols 0..401)
      int col = (bid - 56) * 4 + wid;
      if (col < 402) {
        float wv0 = W[lane * 427 + col];
        float wv1 = W[(lane + 64) * 427 + col];
        float wv2 = W[(lane + 128) * 427 + col];
        float wv3 = (lane < 8) ? W[(lane + 192) * 427 + col] : 0.f;
        float acc[12];
        #pragma unroll
        for (int o = 0; o < 12; ++o) {
          const float* dr = dw + o * 200;
          float a = dr[lane] * wv0 + dr[lane + 64] * wv1 + dr[lane + 128] * wv2;
          if (lane < 8) a += dr[lane + 192] * wv3;
          acc[o] = a;
        }
        #pragma unroll
        for (int s = 1; s < 64; s <<= 1) {
          #pragma unroll
          for (int o = 0; o < 12; ++o) acc[o] += __shfl_xor(acc[o], s, 64);
        }
        if (lane == 0) {
          if (col < 200) {
            int h = col / 40, x = col % 40;
            #pragma unroll
            for (int o = 0; o < 12; ++o) DWhp[o * 320 + h * 64 + x] = f2h(acc[o]);
          } else if (col == 200) {
            #pragma unroll
            for (int o = 0; o < 12; ++o) biasH[o] = acc[o];
          } else if (col < 401) {
            int k = col - 201;
            #pragma unroll
            for (int o = 0; o < 12; ++o) DWtp[o * 224 + k] = f2h(acc[o]);
          } else {
            #pragma unroll
            for (int o = 0; o < 12; ++o) biasT[o] = acc[o];
          }
        }
      }
    } else if (bid < 189) {
      // ---- G: thread-per-(h,x,y); full dw in LDS
      float* dws = (float*)smem;  // 2400 floats
      const float4* dwf4 = reinterpret_cast<const float4*>(dw);
      float4* lds4 = reinterpret_cast<float4*>(dws);
      for (int j = tid; j < 600; j += 256) lds4[j] = dwf4[j];
      __syncthreads();
      int t = (bid - 157) * 256 + tid;
      if (t < 8000) {
        int h = t / 1600, r = t % 1600, x = r / 40, y = r % 40;
        const float* Ub = U + ((h * 40) * 40 + x) * 40 + y;
        float acc[12] = {};
        #pragma unroll 4
        for (int d = 0; d < 40; ++d) {
          float uv = Ub[d * 1600];
          #pragma unroll
          for (int o = 0; o < 12; ++o) acc[o] += dws[o * 200 + h * 40 + d] * uv;
        }
        #pragma unroll
        for (int o = 0; o < 12; ++o)
          Gp[(h * 480 + o * 40 + y) * 64 + x] = f2h(acc[o]);
      }
    } else if (bid < 279) {
      // ---- E: wave per (o,p)
      int e = (bid - 189) * 4 + wid;   // 0..359
      int o = e / 30, p = e % 30;
      float sev[25];
      #pragma unroll
      for (int s = 0; s < 25; ++s) sev[s] = se[p * 25 + s];
      float v = 0.f;
      for (int kk = lane; kk < 200; kk += 64) {
        const float* wrow = W + kk * 427 + 402;
        float wse = 0.f;
        #pragma unroll
        for (int s = 0; s < 25; ++s) wse += wrow[s] * sev[s];
        v += dw[o * 200 + kk] * wse;
      }
      #pragma unroll
      for (int s = 1; s < 64; s <<= 1) v += __shfl_xor(v, s, 64);
      if (lane == 0) E[o * 30 + p] = v;
    } else {
      // ---- pads (uint4 units)
      int p = (bid - 279) * 256 + tid;
      uint4 z = make_uint4(0u, 0u, 0u, 0u);
      if (p < 3072) {            // tail16 [200,224): col200 = 1.0h, rest 0
        int row = p / 3, j = p % 3;
        uint4 v = (j == 0) ? make_uint4(0x00003C00u, 0u, 0u, 0u) : z;
        *reinterpret_cast<uint4*>(tail16 + row * 224 + 200 + j * 8) = v;
      } else if (p < 3072 + 15360) {   // headp [40,64) per group
        int q = p - 3072;
        int row = q / 15, rem = q % 15, h = rem / 3, j = rem % 3;
        *reinterpret_cast<uint4*>(headp + row * 320 + h * 64 + 40 + j * 8) = z;
      } else if (p < 3072 + 15360 + 7200) {  // Gp [40,64)
        int q = p - 3072 - 15360;
        int row = q / 3, j = q % 3;
        *reinterpret_cast<uint4*>(Gp + row * 64 + 40 + j * 8) = z;
      } else if (p < 3072 + 15360 + 7200 + 180) {  // DWhp [40,64)
        int q = p - 3072 - 15360 - 7200;
        int ro = q / 3, j = q % 3, o = ro / 5, h = ro % 5;
        *reinterpret_cast<uint4*>(DWhp + o * 320 + h * 64 + 40 + j * 8) = z;
      }
    }
    // ---- producer finish: publish + count
    __threadfence();
    __syncthreads();
    if (tid == 0)
      __hip_atomic_fetch_add(flag, 1u, __ATOMIC_RELEASE, __HIP_MEMORY_SCOPE_AGENT);
    return;
  }

  // ================= consumer: fused P + main GEMM per (b,o,mt) =================
  unsigned short* Ps = (unsigned short*)smem;   // [64][232]
  int cbid = bid - (int)N_PROD;
  int mt = cbid & 3, ob = cbid >> 2;
  int o = ob % 12, b = ob / 12;

  // zero P cols [201,224) (LDS only — safe before the wait)
  for (int idx = tid; idx < 64 * 23; idx += 256)
    Ps[(idx / 23) * 232 + 201 + idx % 23] = 0;

  if (tid == 0) {
    while (__hip_atomic_load(flag, __ATOMIC_ACQUIRE, __HIP_MEMORY_SCOPE_AGENT) < N_PROD)
      __builtin_amdgcn_s_sleep(8);
  }
  __syncthreads();

  // ---- phase A: wave wid computes P rows [wid*16, wid*16+16)
  {
    const unsigned short* arow = headp + (b * 256 + mt * 64 + wid * 16 + r15) * 320;
    f32x4 accA = {};
    #pragma unroll
    for (int h = 0; h < 5; ++h) {
      f32x4 accY[3] = {};
      #pragma unroll
      for (int ks = 0; ks < 2; ++ks) {
        half8 av = *reinterpret_cast<const half8*>(arow + h * 64 + ks * 32 + g8 * 8);
        #pragma unroll
        for (int yf = 0; yf < 3; ++yf) {
          int yy = yf * 16 + r15;
          int yc = yy < 40 ? yy : 39;
          half8 bv = *reinterpret_cast<const half8*>(
              Gp + (h * 480 + o * 40 + yc) * 64 + ks * 32 + g8 * 8);
          accY[yf] = mfma16(av, bv, accY[yf]);
        }
        half8 bA = *reinterpret_cast<const half8*>(DWhp + o * 320 + h * 64 + ks * 32 + g8 * 8);
        accA = mfma16(av, bA, accA);
      }
      #pragma unroll
      for (int yf = 0; yf < 3; ++yf) {
        int yy = yf * 16 + r15;
        if (yy < 40) {
          int c = h * 40 + yy;
          float dwt = h2f(DWtp[o * 224 + c]);   // Bt fold
          #pragma unroll
          for (int q = 0; q < 4; ++q)
            Ps[(wid * 16 + g8 * 4 + q) * 232 + c] = f2h(accY[yf][q] + dwt);
        }
      }
    }
    if (r15 == 0) {
      float cst = biasH[o] + biasT[o] + db[o];
      #pragma unroll
      for (int q = 0; q < 4; ++q)
        Ps[(wid * 16 + g8 * 4 + q) * 232 + 200] = f2h(accA[q] + cst);  // A fold
    }
  }
  __syncthreads();

  // ---- phase B: main GEMM, wave wid owns output cols [wid*64, +64)
  int nt = wid;
  const uint4* bptr[4];
  #pragma unroll
  for (int h = 0; h < 4; ++h)
    bptr[h] = reinterpret_cast<const uint4*>(
        tail16 + (b * 256 + nt * 64 + h * 16 + r15) * 224);

  f32x4 acc[4][4] = {};
  #pragma unroll
  for (int ks = 0; ks < 7; ++ks) {
    int idx = ks * 4 + g8;
    half8 a[4], bb[4];
    #pragma unroll
    for (int g = 0; g < 4; ++g)
      a[g] = *reinterpret_cast<const half8*>(&Ps[(g * 16 + r15) * 232 + ks * 32 + g8 * 8]);
    #pragma unroll
    for (int h = 0; h < 4; ++h) bb[h] = __builtin_bit_cast(half8, bptr[h][idx]);
    #pragma unroll
    for (int g = 0; g < 4; ++g) {
      #pragma unroll
      for (int h = 0; h < 4; ++h)
        acc[g][h] = mfma16(a[g], bb[h], acc[g][h]);
    }
  }
  const float* Erow = E + o * 30;
  #pragma unroll
  for (int g = 0; g < 4; ++g) {
    #pragma unroll
    for (int q = 0; q < 4; ++q) {
      int m = mt * 64 + g * 16 + g8 * 4 + q;
      #pragma unroll
      for (int h = 0; h < 4; ++h) {
        int n = nt * 64 + h * 16 + r15;
        int dpos = n - m;
        dpos = (dpos < -15) ? -15 : (dpos > 14 ? 14 : dpos);
        out[((b * 12 + o) * 256 + m) * 256 + n] = acc[g][h][q] + Erow[dpos + 15];
      }
    }
  }
}

extern "C" void kernel_launch(void* const* d_in, const int* in_sizes, int n_in,
                              void* d_out, int out_size, void* d_ws, size_t ws_size,
                              hipStream_t stream) {
  (void)in_sizes; (void)n_in; (void)out_size; (void)ws_size;
  const float* wr = (const float*)d_in[0];
  const float* hw = (const float*)d_in[4];
  const float* hb = (const float*)d_in[5];
  const float* tw = (const float*)d_in[6];
  const float* tb = (const float*)d_in[7];
  const float* U  = (const float*)d_in[8];
  const float* se = (const float*)d_in[9];
  const float* W  = (const float*)d_in[10];
  const float* dw = (const float*)d_in[11];
  const float* db = (const float*)d_in[12];

  char* ws = (char*)d_ws;
  unsigned short* headp  = (unsigned short*)(ws + 0);        //   655,360  [1024][320]
  unsigned short* tail16 = (unsigned short*)(ws + 655360);   //   458,752  [1024][224]
  unsigned short* Gp     = (unsigned short*)(ws + 1114112);  //   307,200  [2400][64]
  unsigned short* DWhp   = (unsigned short*)(ws + 1421312);  //     7,680
  unsigned short* DWtp   = (unsigned short*)(ws + 1428992);  //     5,376
  float* biasH           = (float*)(ws + 1434368);           //        64
  float* biasT           = (float*)(ws + 1434432);           //        64
  float* E_ws            = (float*)(ws + 1434496);           //     1,440
  unsigned* flag         = (unsigned*)(ws + 1436160);        //         4

  hipMemsetAsync(flag, 0, 4, stream);
  mega<<<572, 256, 52224, stream>>>(wr, hw, tw, hb, tb, U, W, dw, se, db,
                                    headp, tail16, DWhp, DWtp, biasH, biasT,
                                    E_ws, Gp, flag, (float*)d_out);
}

// Round 11
// 52.006 us; speedup vs baseline: 3.5858x; 3.5858x over previous
//
#include <hip/hip_runtime.h>

typedef _Float16 half8 __attribute__((ext_vector_type(8)));
typedef __fp16   fp16x2 __attribute__((ext_vector_type(2)));
typedef float    f32x4 __attribute__((ext_vector_type(4)));

#define DEV static __device__ __forceinline__

DEV unsigned short f2h(float f) {
  _Float16 h = (_Float16)f;
  return __builtin_bit_cast(unsigned short, h);
}
DEV float h2f(unsigned short u) { return (float)__builtin_bit_cast(_Float16, u); }
DEV float lrelu(float x) { return x > 0.f ? x : 0.01f * x; }
DEV f32x4 mfma16(half8 a, half8 b, f32x4 c) {
  return __builtin_amdgcn_mfma_f32_16x16x32_f16(a, b, c, 0, 0, 0);
}
DEV uint2 pk4(float4 v) {
  fp16x2 a = __builtin_amdgcn_cvt_pkrtz(v.x, v.y);
  fp16x2 b = __builtin_amdgcn_cvt_pkrtz(v.z, v.w);
  return make_uint2(__builtin_bit_cast(unsigned, a), __builtin_bit_cast(unsigned, b));
}

// dims: B=4 N=256 H=768 D=200 NH=5 HD=40 OUT=12
// Two plain launches (R9 structure; R10's single-launch flag protocol REVERTED —
// cross-XCD release/acquire cost ~130us of stall).
// Epilogue algebra folded into main GEMM: Bt->P rows, A+biases+db->P col 200
// (tail col200 = 1.0), E[span] = only epilogue add.

// ================= K1: gemm1 (4-wave 128x64 tiles) + DW + G + E + pads =================
// blocks [0,56): gemm1 | [56,157): DW | [157,189): G | [189,279): E | [279,380): pads
__global__ void __launch_bounds__(256) k1(
    const float* __restrict__ wr, const float* __restrict__ hw,
    const float* __restrict__ tw, const float* __restrict__ hb,
    const float* __restrict__ tb, const float* __restrict__ U,
    const float* __restrict__ W, const float* __restrict__ dw,
    const float* __restrict__ se,
    unsigned short* __restrict__ headp, unsigned short* __restrict__ tail16,
    unsigned short* __restrict__ DWhp, unsigned short* __restrict__ DWtp,
    float* __restrict__ biasH, float* __restrict__ biasT,
    float* __restrict__ E, unsigned short* __restrict__ Gp)
{
  __shared__ __align__(16) char smem[52224];
  int bid = blockIdx.x, tid = threadIdx.x;
  int wid = tid >> 6, lane = tid & 63, r15 = lane & 15, g8 = lane >> 4;

  if (bid < 56) {
    // ---- GEMM1: 128x64 tile, 4 waves (wave = 32-row strip)
    unsigned short* Xs  = (unsigned short*)smem;            // [128][136]
    unsigned short* Wsh = (unsigned short*)(smem + 34816);  // [64][136]
    int mt = bid / 7, nt = bid % 7;
    int rb = mt * 128, cb = nt * 64;
    int xrow = tid >> 1, xseg = tid & 1;
    int wrow = tid >> 2, wseg = tid & 3;
    int c = cb + wrow;
    f32x4 acc[2][4] = {};
    for (int kt = 0; kt < 6; ++kt) {
      int k0 = kt * 128;
      {
        const float4* s = reinterpret_cast<const float4*>(wr + (rb + xrow) * 768 + k0 + xseg * 64);
        uint4* d = reinterpret_cast<uint4*>(&Xs[xrow * 136 + xseg * 64]);
        #pragma unroll
        for (int j = 0; j < 8; ++j) {
          uint2 pa = pk4(s[2 * j]), pb = pk4(s[2 * j + 1]);
          d[j] = make_uint4(pa.x, pa.y, pb.x, pb.y);
        }
      }
      {
        uint4* d = reinterpret_cast<uint4*>(&Wsh[wrow * 136 + wseg * 32]);
        if (c < 400) {
          const float4* s = reinterpret_cast<const float4*>(
              (c < 200 ? hw + c * 768 : tw + (c - 200) * 768) + k0 + wseg * 32);
          #pragma unroll
          for (int j = 0; j < 4; ++j) {
            uint2 pa = pk4(s[2 * j]), pb = pk4(s[2 * j + 1]);
            d[j] = make_uint4(pa.x, pa.y, pb.x, pb.y);
          }
        } else {
          uint4 z = make_uint4(0u, 0u, 0u, 0u);
          #pragma unroll
          for (int j = 0; j < 4; ++j) d[j] = z;
        }
      }
      __syncthreads();
      #pragma unroll
      for (int ks = 0; ks < 4; ++ks) {
        half8 a[2], bb[4];
        #pragma unroll
        for (int g = 0; g < 2; ++g)
          a[g] = *reinterpret_cast<const half8*>(&Xs[(wid * 32 + g * 16 + r15) * 136 + ks * 32 + g8 * 8]);
        #pragma unroll
        for (int h = 0; h < 4; ++h)
          bb[h] = *reinterpret_cast<const half8*>(&Wsh[(h * 16 + r15) * 136 + ks * 32 + g8 * 8]);
        #pragma unroll
        for (int g = 0; g < 2; ++g) {
          #pragma unroll
          for (int h = 0; h < 4; ++h)
            acc[g][h] = mfma16(a[g], bb[h], acc[g][h]);
        }
      }
      __syncthreads();
    }
    #pragma unroll
    for (int h = 0; h < 4; ++h) {
      int cc = cb + h * 16 + r15;
      if (cc < 400) {
        float bias = (cc < 200) ? hb[cc] : tb[cc - 200];
        #pragma unroll
        for (int g = 0; g < 2; ++g) {
          #pragma unroll
          for (int q = 0; q < 4; ++q) {
            int m = rb + wid * 32 + g * 16 + g8 * 4 + q;
            float val = lrelu(acc[g][h][q] + bias);
            if (cc < 200) headp[m * 320 + (cc / 40) * 64 + (cc % 40)] = f2h(val);
            else          tail16[m * 224 + (cc - 200)] = f2h(val);
          }
        }
      }
    }
    return;
  }
  if (bid < 157) {
    // ---- DW: wave-per-column (cols 0..401)
    int col = (bid - 56) * 4 + wid;
    if (col < 402) {
      float wv0 = W[lane * 427 + col];
      float wv1 = W[(lane + 64) * 427 + col];
      float wv2 = W[(lane + 128) * 427 + col];
      float wv3 = (lane < 8) ? W[(lane + 192) * 427 + col] : 0.f;
      float acc[12];
      #pragma unroll
      for (int o = 0; o < 12; ++o) {
        const float* dr = dw + o * 200;
        float a = dr[lane] * wv0 + dr[lane + 64] * wv1 + dr[lane + 128] * wv2;
        if (lane < 8) a += dr[lane + 192] * wv3;
        acc[o] = a;
      }
      #pragma unroll
      for (int s = 1; s < 64; s <<= 1) {
        #pragma unroll
        for (int o = 0; o < 12; ++o) acc[o] += __shfl_xor(acc[o], s, 64);
      }
      if (lane == 0) {
        if (col < 200) {
          int h = col / 40, x = col % 40;
          #pragma unroll
          for (int o = 0; o < 12; ++o) DWhp[o * 320 + h * 64 + x] = f2h(acc[o]);
        } else if (col == 200) {
          #pragma unroll
          for (int o = 0; o < 12; ++o) biasH[o] = acc[o];
        } else if (col < 401) {
          int k = col - 201;
          #pragma unroll
          for (int o = 0; o < 12; ++o) DWtp[o * 224 + k] = f2h(acc[o]);
        } else {
          #pragma unroll
          for (int o = 0; o < 12; ++o) biasT[o] = acc[o];
        }
      }
    }
    return;
  }
  if (bid < 189) {
    // ---- G: thread-per-(h,x,y); full dw in LDS
    float* dws = (float*)smem;  // 2400 floats
    const float4* dwf4 = reinterpret_cast<const float4*>(dw);
    float4* lds4 = reinterpret_cast<float4*>(dws);
    for (int j = tid; j < 600; j += 256) lds4[j] = dwf4[j];
    __syncthreads();
    int t = (bid - 157) * 256 + tid;
    if (t < 8000) {
      int h = t / 1600, r = t % 1600, x = r / 40, y = r % 40;
      const float* Ub = U + ((h * 40) * 40 + x) * 40 + y;
      float acc[12] = {};
      #pragma unroll 4
      for (int d = 0; d < 40; ++d) {
        float uv = Ub[d * 1600];
        #pragma unroll
        for (int o = 0; o < 12; ++o) acc[o] += dws[o * 200 + h * 40 + d] * uv;
      }
      #pragma unroll
      for (int o = 0; o < 12; ++o)
        Gp[(h * 480 + o * 40 + y) * 64 + x] = f2h(acc[o]);
    }
    return;
  }
  if (bid < 279) {
    // ---- E: wave per (o,p)
    int e = (bid - 189) * 4 + wid;   // 0..359
    int o = e / 30, p = e % 30;
    float sev[25];
    #pragma unroll
    for (int s = 0; s < 25; ++s) sev[s] = se[p * 25 + s];
    float v = 0.f;
    for (int kk = lane; kk < 200; kk += 64) {
      const float* wrow = W + kk * 427 + 402;
      float wse = 0.f;
      #pragma unroll
      for (int s = 0; s < 25; ++s) wse += wrow[s] * sev[s];
      v += dw[o * 200 + kk] * wse;
    }
    #pragma unroll
    for (int s = 1; s < 64; s <<= 1) v += __shfl_xor(v, s, 64);
    if (lane == 0) E[o * 30 + p] = v;
    return;
  }
  {
    // ---- pads (uint4 units)
    int p = (bid - 279) * 256 + tid;
    uint4 z = make_uint4(0u, 0u, 0u, 0u);
    if (p < 3072) {            // tail16 [200,224): col200 = 1.0h, rest 0
      int row = p / 3, j = p % 3;
      uint4 v = (j == 0) ? make_uint4(0x00003C00u, 0u, 0u, 0u) : z;
      *reinterpret_cast<uint4*>(tail16 + row * 224 + 200 + j * 8) = v;
    } else if (p < 3072 + 15360) {   // headp [40,64) per group
      int q = p - 3072;
      int row = q / 15, rem = q % 15, h = rem / 3, j = rem % 3;
      *reinterpret_cast<uint4*>(headp + row * 320 + h * 64 + 40 + j * 8) = z;
    } else if (p < 3072 + 15360 + 7200) {  // Gp [40,64)
      int q = p - 3072 - 15360;
      int row = q / 3, j = q % 3;
      *reinterpret_cast<uint4*>(Gp + row * 64 + 40 + j * 8) = z;
    } else if (p < 3072 + 15360 + 7200 + 180) {  // DWhp [40,64)
      int q = p - 3072 - 15360 - 7200;
      int ro = q / 3, j = q % 3, o = ro / 5, h = ro % 5;
      *reinterpret_cast<uint4*>(DWhp + o * 320 + h * 64 + 40 + j * 8) = z;
    }
    return;
  }
}

// ================= K3: fused P + main GEMM per (b,o,mt) block =================
__global__ void __launch_bounds__(256) k3(
    const unsigned short* __restrict__ headp, const unsigned short* __restrict__ tail16,
    const unsigned short* __restrict__ Gp, const unsigned short* __restrict__ DWhp,
    const unsigned short* __restrict__ DWtp, const float* __restrict__ biasH,
    const float* __restrict__ biasT, const float* __restrict__ E,
    const float* __restrict__ db, float* __restrict__ out)
{
  __shared__ __align__(16) unsigned short Ps[64 * 232];
  int bid = blockIdx.x, tid = threadIdx.x;
  int mt = bid & 3, ob = bid >> 2;
  int o = ob % 12, b = ob / 12;
  int wid = tid >> 6, lane = tid & 63, r15 = lane & 15, g8 = lane >> 4;

  // zero P cols [201,224)
  for (int idx = tid; idx < 64 * 23; idx += 256)
    Ps[(idx / 23) * 232 + 201 + idx % 23] = 0;

  // ---- phase A: wave wid computes P rows [wid*16, wid*16+16)
  {
    const unsigned short* arow = headp + (b * 256 + mt * 64 + wid * 16 + r15) * 320;
    f32x4 accA = {};
    #pragma unroll
    for (int h = 0; h < 5; ++h) {
      f32x4 accY[3] = {};
      #pragma unroll
      for (int ks = 0; ks < 2; ++ks) {
        half8 av = *reinterpret_cast<const half8*>(arow + h * 64 + ks * 32 + g8 * 8);
        #pragma unroll
        for (int yf = 0; yf < 3; ++yf) {
          int yy = yf * 16 + r15;
          int yc = yy < 40 ? yy : 39;
          half8 bv = *reinterpret_cast<const half8*>(
              Gp + (h * 480 + o * 40 + yc) * 64 + ks * 32 + g8 * 8);
          accY[yf] = mfma16(av, bv, accY[yf]);
        }
        half8 bA = *reinterpret_cast<const half8*>(DWhp + o * 320 + h * 64 + ks * 32 + g8 * 8);
        accA = mfma16(av, bA, accA);
      }
      #pragma unroll
      for (int yf = 0; yf < 3; ++yf) {
        int yy = yf * 16 + r15;
        if (yy < 40) {
          int c = h * 40 + yy;
          float dwt = h2f(DWtp[o * 224 + c]);   // Bt fold
          #pragma unroll
          for (int q = 0; q < 4; ++q)
            Ps[(wid * 16 + g8 * 4 + q) * 232 + c] = f2h(accY[yf][q] + dwt);
        }
      }
    }
    if (r15 == 0) {
      float cst = biasH[o] + biasT[o] + db[o];
      #pragma unroll
      for (int q = 0; q < 4; ++q)
        Ps[(wid * 16 + g8 * 4 + q) * 232 + 200] = f2h(accA[q] + cst);  // A fold
    }
  }
  __syncthreads();

  // ---- phase B: main GEMM, wave wid owns output cols [wid*64, +64)
  int nt = wid;
  const uint4* bptr[4];
  #pragma unroll
  for (int h = 0; h < 4; ++h)
    bptr[h] = reinterpret_cast<const uint4*>(
        tail16 + (b * 256 + nt * 64 + h * 16 + r15) * 224);

  f32x4 acc[4][4] = {};
  #pragma unroll
  for (int ks = 0; ks < 7; ++ks) {
    int idx = ks * 4 + g8;
    half8 a[4], bb[4];
    #pragma unroll
    for (int g = 0; g < 4; ++g)
      a[g] = *reinterpret_cast<const half8*>(&Ps[(g * 16 + r15) * 232 + ks * 32 + g8 * 8]);
    #pragma unroll
    for (int h = 0; h < 4; ++h) bb[h] = __builtin_bit_cast(half8, bptr[h][idx]);
    #pragma unroll
    for (int g = 0; g < 4; ++g) {
      #pragma unroll
      for (int h = 0; h < 4; ++h)
        acc[g][h] = mfma16(a[g], bb[h], acc[g][h]);
    }
  }
  const float* Erow = E + o * 30;
  #pragma unroll
  for (int g = 0; g < 4; ++g) {
    #pragma unroll
    for (int q = 0; q < 4; ++q) {
      int m = mt * 64 + g * 16 + g8 * 4 + q;
      #pragma unroll
      for (int h = 0; h < 4; ++h) {
        int n = nt * 64 + h * 16 + r15;
        int dpos = n - m;
        dpos = (dpos < -15) ? -15 : (dpos > 14 ? 14 : dpos);
        out[((b * 12 + o) * 256 + m) * 256 + n] = acc[g][h][q] + Erow[dpos + 15];
      }
    }
  }
}

extern "C" void kernel_launch(void* const* d_in, const int* in_sizes, int n_in,
                              void* d_out, int out_size, void* d_ws, size_t ws_size,
                              hipStream_t stream) {
  (void)in_sizes; (void)n_in; (void)out_size; (void)ws_size;
  const float* wr = (const float*)d_in[0];
  const float* hw = (const float*)d_in[4];
  const float* hb = (const float*)d_in[5];
  const float* tw = (const float*)d_in[6];
  const float* tb = (const float*)d_in[7];
  const float* U  = (const float*)d_in[8];
  const float* se = (const float*)d_in[9];
  const float* W  = (const float*)d_in[10];
  const float* dw = (const float*)d_in[11];
  const float* db = (const float*)d_in[12];

  char* ws = (char*)d_ws;
  unsigned short* headp  = (unsigned short*)(ws + 0);        //   655,360  [1024][320]
  unsigned short* tail16 = (unsigned short*)(ws + 655360);   //   458,752  [1024][224]
  unsigned short* Gp     = (unsigned short*)(ws + 1114112);  //   307,200  [2400][64]
  unsigned short* DWhp   = (unsigned short*)(ws + 1421312);  //     7,680
  unsigned short* DWtp   = (unsigned short*)(ws + 1428992);  //     5,376
  float* biasH           = (float*)(ws + 1434368);           //        64
  float* biasT           = (float*)(ws + 1434432);           //        64
  float* E_ws            = (float*)(ws + 1434496);           //     1,440  -> end ~1.44 MB

  k1<<<380, 256, 0, stream>>>(wr, hw, tw, hb, tb, U, W, dw, se,
                              headp, tail16, DWhp, DWtp, biasH, biasT, E_ws, Gp);
  k3<<<192, 256, 0, stream>>>(headp, tail16, Gp, DWhp, DWtp, biasH, biasT,
                              E_ws, db, (float*)d_out);
}

// Round 12
// 36.401 us; speedup vs baseline: 5.1229x; 1.4287x over previous
//
#include <hip/hip_runtime.h>

typedef _Float16 half8 __attribute__((ext_vector_type(8)));
typedef __fp16   fp16x2 __attribute__((ext_vector_type(2)));
typedef float    f32x4 __attribute__((ext_vector_type(4)));

#define DEV static __device__ __forceinline__

DEV unsigned short f2h(float f) {
  _Float16 h = (_Float16)f;
  return __builtin_bit_cast(unsigned short, h);
}
DEV float h2f(unsigned short u) { return (float)__builtin_bit_cast(_Float16, u); }
DEV float lrelu(float x) { return x > 0.f ? x : 0.01f * x; }
DEV f32x4 mfma16(half8 a, half8 b, f32x4 c) {
  return __builtin_amdgcn_mfma_f32_16x16x32_f16(a, b, c, 0, 0, 0);
}
DEV uint2 pk4(float4 v) {
  fp16x2 a = __builtin_amdgcn_cvt_pkrtz(v.x, v.y);
  fp16x2 b = __builtin_amdgcn_cvt_pkrtz(v.z, v.w);
  return make_uint2(__builtin_bit_cast(unsigned, a), __builtin_bit_cast(unsigned, b));
}

// dims: B=4 N=256 H=768 D=200 NH=5 HD=40 OUT=12
// Two plain launches. Epilogue algebra folded into main GEMM: Bt->P rows,
// A+biases+db->P col 200 (tail col200=1.0), E[span] = only epilogue add.

// ================= K1: gemm1 (4-wave coop-staged 64x64 tiles) + DW + G + E + pads =================
// blocks [0,112): gemm1 | [112,213): DW | [213,245): G | [245,335): E | [335,436): pads
__global__ void __launch_bounds__(256) k1(
    const float* __restrict__ wr, const float* __restrict__ hw,
    const float* __restrict__ tw, const float* __restrict__ hb,
    const float* __restrict__ tb, const float* __restrict__ U,
    const float* __restrict__ W, const float* __restrict__ dw,
    const float* __restrict__ se,
    unsigned short* __restrict__ headp, unsigned short* __restrict__ tail16,
    unsigned short* __restrict__ DWhp, unsigned short* __restrict__ DWtp,
    float* __restrict__ biasH, float* __restrict__ biasT,
    float* __restrict__ E, unsigned short* __restrict__ Gp)
{
  __shared__ __align__(16) char smem[34816];
  int bid = blockIdx.x, tid = threadIdx.x;
  int wid = tid >> 6, lane = tid & 63, r15 = lane & 15, g8 = lane >> 4;

  if (bid < 112) {
    // ---- GEMM1: 64x64 tile, 256 threads coop-stage, wave w computes 16-col strip
    unsigned short* Xs  = (unsigned short*)smem;            // [64][136]
    unsigned short* Wsh = (unsigned short*)(smem + 17408);  // [64][136]
    int mt = bid / 7, nt = bid % 7;
    int rb = mt * 64, cb = nt * 64;
    int srow = tid >> 2, sseg = tid & 3;
    int c = cb + srow;
    f32x4 acc[4] = {};
    for (int kt = 0; kt < 6; ++kt) {
      int k0 = kt * 128;
      {
        const float4* s = reinterpret_cast<const float4*>(wr + (rb + srow) * 768 + k0 + sseg * 32);
        uint4* d = reinterpret_cast<uint4*>(&Xs[srow * 136 + sseg * 32]);
        #pragma unroll
        for (int j = 0; j < 4; ++j) {
          uint2 pa = pk4(s[2 * j]), pb = pk4(s[2 * j + 1]);
          d[j] = make_uint4(pa.x, pa.y, pb.x, pb.y);
        }
      }
      {
        uint4* d = reinterpret_cast<uint4*>(&Wsh[srow * 136 + sseg * 32]);
        if (c < 400) {
          const float4* s = reinterpret_cast<const float4*>(
              (c < 200 ? hw + c * 768 : tw + (c - 200) * 768) + k0 + sseg * 32);
          #pragma unroll
          for (int j = 0; j < 4; ++j) {
            uint2 pa = pk4(s[2 * j]), pb = pk4(s[2 * j + 1]);
            d[j] = make_uint4(pa.x, pa.y, pb.x, pb.y);
          }
        } else {
          uint4 z = make_uint4(0u, 0u, 0u, 0u);
          #pragma unroll
          for (int j = 0; j < 4; ++j) d[j] = z;
        }
      }
      __syncthreads();
      #pragma unroll
      for (int ks = 0; ks < 4; ++ks) {
        half8 bb = *reinterpret_cast<const half8*>(&Wsh[(wid * 16 + r15) * 136 + ks * 32 + g8 * 8]);
        #pragma unroll
        for (int g = 0; g < 4; ++g) {
          half8 a = *reinterpret_cast<const half8*>(&Xs[(g * 16 + r15) * 136 + ks * 32 + g8 * 8]);
          acc[g] = mfma16(a, bb, acc[g]);
        }
      }
      __syncthreads();
    }
    int cc = cb + wid * 16 + r15;
    if (cc < 400) {
      float bias = (cc < 200) ? hb[cc] : tb[cc - 200];
      #pragma unroll
      for (int g = 0; g < 4; ++g) {
        #pragma unroll
        for (int q = 0; q < 4; ++q) {
          int m = rb + g * 16 + g8 * 4 + q;
          float val = lrelu(acc[g][q] + bias);
          if (cc < 200) headp[m * 320 + (cc / 40) * 64 + (cc % 40)] = f2h(val);
          else          tail16[m * 224 + (cc - 200)] = f2h(val);
        }
      }
    }
    return;
  }
  if (bid < 213) {
    // ---- DW: wave-per-column (cols 0..401)
    int col = (bid - 112) * 4 + wid;
    if (col < 402) {
      float wv0 = W[lane * 427 + col];
      float wv1 = W[(lane + 64) * 427 + col];
      float wv2 = W[(lane + 128) * 427 + col];
      float wv3 = (lane < 8) ? W[(lane + 192) * 427 + col] : 0.f;
      float acc[12];
      #pragma unroll
      for (int o = 0; o < 12; ++o) {
        const float* dr = dw + o * 200;
        float a = dr[lane] * wv0 + dr[lane + 64] * wv1 + dr[lane + 128] * wv2;
        if (lane < 8) a += dr[lane + 192] * wv3;
        acc[o] = a;
      }
      #pragma unroll
      for (int s = 1; s < 64; s <<= 1) {
        #pragma unroll
        for (int o = 0; o < 12; ++o) acc[o] += __shfl_xor(acc[o], s, 64);
      }
      if (lane == 0) {
        if (col < 200) {
          int h = col / 40, x = col % 40;
          #pragma unroll
          for (int o = 0; o < 12; ++o) DWhp[o * 320 + h * 64 + x] = f2h(acc[o]);
        } else if (col == 200) {
          #pragma unroll
          for (int o = 0; o < 12; ++o) biasH[o] = acc[o];
        } else if (col < 401) {
          int k = col - 201;
          #pragma unroll
          for (int o = 0; o < 12; ++o) DWtp[o * 224 + k] = f2h(acc[o]);
        } else {
          #pragma unroll
          for (int o = 0; o < 12; ++o) biasT[o] = acc[o];
        }
      }
    }
    return;
  }
  if (bid < 245) {
    // ---- G: thread-per-(h,x,y); full dw in LDS
    float* dws = (float*)smem;  // 2400 floats
    const float4* dwf4 = reinterpret_cast<const float4*>(dw);
    float4* lds4 = reinterpret_cast<float4*>(dws);
    for (int j = tid; j < 600; j += 256) lds4[j] = dwf4[j];
    __syncthreads();
    int t = (bid - 213) * 256 + tid;
    if (t < 8000) {
      int h = t / 1600, r = t % 1600, x = r / 40, y = r % 40;
      const float* Ub = U + ((h * 40) * 40 + x) * 40 + y;
      float acc[12] = {};
      #pragma unroll 4
      for (int d = 0; d < 40; ++d) {
        float uv = Ub[d * 1600];
        #pragma unroll
        for (int o = 0; o < 12; ++o) acc[o] += dws[o * 200 + h * 40 + d] * uv;
      }
      #pragma unroll
      for (int o = 0; o < 12; ++o)
        Gp[(h * 480 + o * 40 + y) * 64 + x] = f2h(acc[o]);
    }
    return;
  }
  if (bid < 335) {
    // ---- E: wave per (o,p)
    int e = (bid - 245) * 4 + wid;   // 0..359
    int o = e / 30, p = e % 30;
    float sev[25];
    #pragma unroll
    for (int s = 0; s < 25; ++s) sev[s] = se[p * 25 + s];
    float v = 0.f;
    for (int kk = lane; kk < 200; kk += 64) {
      const float* wrow = W + kk * 427 + 402;
      float wse = 0.f;
      #pragma unroll
      for (int s = 0; s < 25; ++s) wse += wrow[s] * sev[s];
      v += dw[o * 200 + kk] * wse;
    }
    #pragma unroll
    for (int s = 1; s < 64; s <<= 1) v += __shfl_xor(v, s, 64);
    if (lane == 0) E[o * 30 + p] = v;
    return;
  }
  {
    // ---- pads (uint4 units)
    int p = (bid - 335) * 256 + tid;
    uint4 z = make_uint4(0u, 0u, 0u, 0u);
    if (p < 3072) {            // tail16 [200,224): col200 = 1.0h, rest 0
      int row = p / 3, j = p % 3;
      uint4 v = (j == 0) ? make_uint4(0x00003C00u, 0u, 0u, 0u) : z;
      *reinterpret_cast<uint4*>(tail16 + row * 224 + 200 + j * 8) = v;
    } else if (p < 3072 + 15360) {   // headp [40,64) per group
      int q = p - 3072;
      int row = q / 15, rem = q % 15, h = rem / 3, j = rem % 3;
      *reinterpret_cast<uint4*>(headp + row * 320 + h * 64 + 40 + j * 8) = z;
    } else if (p < 3072 + 15360 + 7200) {  // Gp [40,64)
      int q = p - 3072 - 15360;
      int row = q / 3, j = q % 3;
      *reinterpret_cast<uint4*>(Gp + row * 64 + 40 + j * 8) = z;
    } else if (p < 3072 + 15360 + 7200 + 180) {  // DWhp [40,64)
      int q = p - 3072 - 15360 - 7200;
      int ro = q / 3, j = q % 3, o = ro / 5, h = ro % 5;
      *reinterpret_cast<uint4*>(DWhp + o * 320 + h * 64 + 40 + j * 8) = z;
    }
    return;
  }
}

// ================= K3: fused P + main GEMM per (b,o,mt); B-side staged in LDS =================
__global__ void __launch_bounds__(256) k3(
    const unsigned short* __restrict__ headp, const unsigned short* __restrict__ tail16,
    const unsigned short* __restrict__ Gp, const unsigned short* __restrict__ DWhp,
    const unsigned short* __restrict__ DWtp, const float* __restrict__ biasH,
    const float* __restrict__ biasT, const float* __restrict__ E,
    const float* __restrict__ db, float* __restrict__ out)
{
  __shared__ __align__(16) unsigned short Ps[64 * 232];   // 29696 B
  __shared__ __align__(16) unsigned short Gs[200 * 72];   // 28800 B (stride 72: bank-safe)
  __shared__ __align__(16) unsigned short DWh_s[320];     //   640 B
  __shared__ __align__(16) unsigned short DWt_s[224];     //   448 B
  int bid = blockIdx.x, tid = threadIdx.x;
  int mt = bid & 3, ob = bid >> 2;
  int o = ob % 12, b = ob / 12;
  int wid = tid >> 6, lane = tid & 63, r15 = lane & 15, g8 = lane >> 4;

  // ---- coop stage: Gp[o] tile (200 rows x 64), DWh[o], DWt[o]; zero Ps pad cols
  for (int idx = tid; idx < 1600; idx += 256) {
    int row = idx >> 3, j = idx & 7;
    reinterpret_cast<uint4*>(&Gs[row * 72])[j] =
        reinterpret_cast<const uint4*>(Gp + ((row / 40) * 480 + o * 40 + (row % 40)) * 64)[j];
  }
  if (tid < 40)
    reinterpret_cast<uint4*>(DWh_s)[tid] = reinterpret_cast<const uint4*>(DWhp + o * 320)[tid];
  else if (tid >= 64 && tid < 92)
    reinterpret_cast<uint4*>(DWt_s)[tid - 64] = reinterpret_cast<const uint4*>(DWtp + o * 224)[tid - 64];
  for (int idx = tid; idx < 64 * 23; idx += 256)
    Ps[(idx / 23) * 232 + 201 + idx % 23] = 0;
  __syncthreads();

  // ---- phase A: wave wid computes P rows [wid*16, wid*16+16)
  {
    const unsigned short* arow = headp + (b * 256 + mt * 64 + wid * 16 + r15) * 320;
    f32x4 accA = {};
    #pragma unroll
    for (int h = 0; h < 5; ++h) {
      f32x4 accY[3] = {};
      #pragma unroll
      for (int ks = 0; ks < 2; ++ks) {
        half8 av = *reinterpret_cast<const half8*>(arow + h * 64 + ks * 32 + g8 * 8);
        #pragma unroll
        for (int yf = 0; yf < 3; ++yf) {
          int yy = yf * 16 + r15;
          int yc = yy < 40 ? yy : 39;
          half8 bv = *reinterpret_cast<const half8*>(&Gs[(h * 40 + yc) * 72 + ks * 32 + g8 * 8]);
          accY[yf] = mfma16(av, bv, accY[yf]);
        }
        half8 bA = *reinterpret_cast<const half8*>(&DWh_s[h * 64 + ks * 32 + g8 * 8]);
        accA = mfma16(av, bA, accA);
      }
      #pragma unroll
      for (int yf = 0; yf < 3; ++yf) {
        int yy = yf * 16 + r15;
        if (yy < 40) {
          int c = h * 40 + yy;
          float dwt = h2f(DWt_s[c]);   // Bt fold
          #pragma unroll
          for (int q = 0; q < 4; ++q)
            Ps[(wid * 16 + g8 * 4 + q) * 232 + c] = f2h(accY[yf][q] + dwt);
        }
      }
    }
    if (r15 == 0) {
      float cst = biasH[o] + biasT[o] + db[o];
      #pragma unroll
      for (int q = 0; q < 4; ++q)
        Ps[(wid * 16 + g8 * 4 + q) * 232 + 200] = f2h(accA[q] + cst);  // A fold
    }
  }
  __syncthreads();

  // ---- phase B: main GEMM, wave wid owns output cols [wid*64, +64)
  int nt = wid;
  const uint4* bptr[4];
  #pragma unroll
  for (int h = 0; h < 4; ++h)
    bptr[h] = reinterpret_cast<const uint4*>(
        tail16 + (b * 256 + nt * 64 + h * 16 + r15) * 224);

  f32x4 acc[4][4] = {};
  #pragma unroll
  for (int ks = 0; ks < 7; ++ks) {
    int idx = ks * 4 + g8;
    half8 a[4], bb[4];
    #pragma unroll
    for (int g = 0; g < 4; ++g)
      a[g] = *reinterpret_cast<const half8*>(&Ps[(g * 16 + r15) * 232 + ks * 32 + g8 * 8]);
    #pragma unroll
    for (int h = 0; h < 4; ++h) bb[h] = __builtin_bit_cast(half8, bptr[h][idx]);
    #pragma unroll
    for (int g = 0; g < 4; ++g) {
      #pragma unroll
      for (int h = 0; h < 4; ++h)
        acc[g][h] = mfma16(a[g], bb[h], acc[g][h]);
    }
  }
  const float* Erow = E + o * 30;
  #pragma unroll
  for (int g = 0; g < 4; ++g) {
    #pragma unroll
    for (int q = 0; q < 4; ++q) {
      int m = mt * 64 + g * 16 + g8 * 4 + q;
      #pragma unroll
      for (int h = 0; h < 4; ++h) {
        int n = nt * 64 + h * 16 + r15;
        int dpos = n - m;
        dpos = (dpos < -15) ? -15 : (dpos > 14 ? 14 : dpos);
        out[((b * 12 + o) * 256 + m) * 256 + n] = acc[g][h][q] + Erow[dpos + 15];
      }
    }
  }
}

extern "C" void kernel_launch(void* const* d_in, const int* in_sizes, int n_in,
                              void* d_out, int out_size, void* d_ws, size_t ws_size,
                              hipStream_t stream) {
  (void)in_sizes; (void)n_in; (void)out_size; (void)ws_size;
  const float* wr = (const float*)d_in[0];
  const float* hw = (const float*)d_in[4];
  const float* hb = (const float*)d_in[5];
  const float* tw = (const float*)d_in[6];
  const float* tb = (const float*)d_in[7];
  const float* U  = (const float*)d_in[8];
  const float* se = (const float*)d_in[9];
  const float* W  = (const float*)d_in[10];
  const float* dw = (const float*)d_in[11];
  const float* db = (const float*)d_in[12];

  char* ws = (char*)d_ws;
  unsigned short* headp  = (unsigned short*)(ws + 0);        //   655,360  [1024][320]
  unsigned short* tail16 = (unsigned short*)(ws + 655360);   //   458,752  [1024][224]
  unsigned short* Gp     = (unsigned short*)(ws + 1114112);  //   307,200  [2400][64]
  unsigned short* DWhp   = (unsigned short*)(ws + 1421312);  //     7,680
  unsigned short* DWtp   = (unsigned short*)(ws + 1428992);  //     5,376
  float* biasH           = (float*)(ws + 1434368);           //        64
  float* biasT           = (float*)(ws + 1434432);           //        64
  float* E_ws            = (float*)(ws + 1434496);           //     1,440  -> end ~1.44 MB

  k1<<<436, 256, 0, stream>>>(wr, hw, tw, hb, tb, U, W, dw, se,
                              headp, tail16, DWhp, DWtp, biasH, biasT, E_ws, Gp);
  k3<<<192, 256, 0, stream>>>(headp, tail16, Gp, DWhp, DWtp, biasH, biasT,
                              E_ws, db, (float*)d_out);
}

// Round 13
// 35.872 us; speedup vs baseline: 5.1985x; 1.0148x over previous
//
#include <hip/hip_runtime.h>

typedef _Float16 half8 __attribute__((ext_vector_type(8)));
typedef __fp16   fp16x2 __attribute__((ext_vector_type(2)));
typedef float    f32x4 __attribute__((ext_vector_type(4)));

#define DEV static __device__ __forceinline__

DEV unsigned short f2h(float f) {
  _Float16 h = (_Float16)f;
  return __builtin_bit_cast(unsigned short, h);
}
DEV float h2f(unsigned short u) { return (float)__builtin_bit_cast(_Float16, u); }
DEV float lrelu(float x) { return x > 0.f ? x : 0.01f * x; }
DEV f32x4 mfma16(half8 a, half8 b, f32x4 c) {
  return __builtin_amdgcn_mfma_f32_16x16x32_f16(a, b, c, 0, 0, 0);
}
DEV uint2 pk4(float4 v) {
  fp16x2 a = __builtin_amdgcn_cvt_pkrtz(v.x, v.y);
  fp16x2 b = __builtin_amdgcn_cvt_pkrtz(v.z, v.w);
  return make_uint2(__builtin_bit_cast(unsigned, a), __builtin_bit_cast(unsigned, b));
}

// dims: B=4 N=256 H=768 D=200 NH=5 HD=40 OUT=12
// Two plain launches. Epilogue algebra folded into main GEMM: Bt->P rows,
// A+biases+db->P col 200 (tail col200=1.0), E[span] = only epilogue add.
// R13: k3 n-split into 384 blocks (phase A duplicated per n-half) for full
// CU coverage; phase B per wave = 32-col strip.

// ================= K1: gemm1 (4-wave coop-staged 64x64 tiles) + DW + G + E + pads =================
// blocks [0,112): gemm1 | [112,213): DW | [213,245): G | [245,335): E | [335,436): pads
__global__ void __launch_bounds__(256) k1(
    const float* __restrict__ wr, const float* __restrict__ hw,
    const float* __restrict__ tw, const float* __restrict__ hb,
    const float* __restrict__ tb, const float* __restrict__ U,
    const float* __restrict__ W, const float* __restrict__ dw,
    const float* __restrict__ se,
    unsigned short* __restrict__ headp, unsigned short* __restrict__ tail16,
    unsigned short* __restrict__ DWhp, unsigned short* __restrict__ DWtp,
    float* __restrict__ biasH, float* __restrict__ biasT,
    float* __restrict__ E, unsigned short* __restrict__ Gp)
{
  __shared__ __align__(16) char smem[34816];
  int bid = blockIdx.x, tid = threadIdx.x;
  int wid = tid >> 6, lane = tid & 63, r15 = lane & 15, g8 = lane >> 4;

  if (bid < 112) {
    // ---- GEMM1: 64x64 tile, 256 threads coop-stage, wave w computes 16-col strip
    unsigned short* Xs  = (unsigned short*)smem;            // [64][136]
    unsigned short* Wsh = (unsigned short*)(smem + 17408);  // [64][136]
    int mt = bid / 7, nt = bid % 7;
    int rb = mt * 64, cb = nt * 64;
    int srow = tid >> 2, sseg = tid & 3;
    int c = cb + srow;
    f32x4 acc[4] = {};
    for (int kt = 0; kt < 6; ++kt) {
      int k0 = kt * 128;
      {
        const float4* s = reinterpret_cast<const float4*>(wr + (rb + srow) * 768 + k0 + sseg * 32);
        uint4* d = reinterpret_cast<uint4*>(&Xs[srow * 136 + sseg * 32]);
        #pragma unroll
        for (int j = 0; j < 4; ++j) {
          uint2 pa = pk4(s[2 * j]), pb = pk4(s[2 * j + 1]);
          d[j] = make_uint4(pa.x, pa.y, pb.x, pb.y);
        }
      }
      {
        uint4* d = reinterpret_cast<uint4*>(&Wsh[srow * 136 + sseg * 32]);
        if (c < 400) {
          const float4* s = reinterpret_cast<const float4*>(
              (c < 200 ? hw + c * 768 : tw + (c - 200) * 768) + k0 + sseg * 32);
          #pragma unroll
          for (int j = 0; j < 4; ++j) {
            uint2 pa = pk4(s[2 * j]), pb = pk4(s[2 * j + 1]);
            d[j] = make_uint4(pa.x, pa.y, pb.x, pb.y);
          }
        } else {
          uint4 z = make_uint4(0u, 0u, 0u, 0u);
          #pragma unroll
          for (int j = 0; j < 4; ++j) d[j] = z;
        }
      }
      __syncthreads();
      #pragma unroll
      for (int ks = 0; ks < 4; ++ks) {
        half8 bb = *reinterpret_cast<const half8*>(&Wsh[(wid * 16 + r15) * 136 + ks * 32 + g8 * 8]);
        #pragma unroll
        for (int g = 0; g < 4; ++g) {
          half8 a = *reinterpret_cast<const half8*>(&Xs[(g * 16 + r15) * 136 + ks * 32 + g8 * 8]);
          acc[g] = mfma16(a, bb, acc[g]);
        }
      }
      __syncthreads();
    }
    int cc = cb + wid * 16 + r15;
    if (cc < 400) {
      float bias = (cc < 200) ? hb[cc] : tb[cc - 200];
      #pragma unroll
      for (int g = 0; g < 4; ++g) {
        #pragma unroll
        for (int q = 0; q < 4; ++q) {
          int m = rb + g * 16 + g8 * 4 + q;
          float val = lrelu(acc[g][q] + bias);
          if (cc < 200) headp[m * 320 + (cc / 40) * 64 + (cc % 40)] = f2h(val);
          else          tail16[m * 224 + (cc - 200)] = f2h(val);
        }
      }
    }
    return;
  }
  if (bid < 213) {
    // ---- DW: wave-per-column (cols 0..401)
    int col = (bid - 112) * 4 + wid;
    if (col < 402) {
      float wv0 = W[lane * 427 + col];
      float wv1 = W[(lane + 64) * 427 + col];
      float wv2 = W[(lane + 128) * 427 + col];
      float wv3 = (lane < 8) ? W[(lane + 192) * 427 + col] : 0.f;
      float acc[12];
      #pragma unroll
      for (int o = 0; o < 12; ++o) {
        const float* dr = dw + o * 200;
        float a = dr[lane] * wv0 + dr[lane + 64] * wv1 + dr[lane + 128] * wv2;
        if (lane < 8) a += dr[lane + 192] * wv3;
        acc[o] = a;
      }
      #pragma unroll
      for (int s = 1; s < 64; s <<= 1) {
        #pragma unroll
        for (int o = 0; o < 12; ++o) acc[o] += __shfl_xor(acc[o], s, 64);
      }
      if (lane == 0) {
        if (col < 200) {
          int h = col / 40, x = col % 40;
          #pragma unroll
          for (int o = 0; o < 12; ++o) DWhp[o * 320 + h * 64 + x] = f2h(acc[o]);
        } else if (col == 200) {
          #pragma unroll
          for (int o = 0; o < 12; ++o) biasH[o] = acc[o];
        } else if (col < 401) {
          int k = col - 201;
          #pragma unroll
          for (int o = 0; o < 12; ++o) DWtp[o * 224 + k] = f2h(acc[o]);
        } else {
          #pragma unroll
          for (int o = 0; o < 12; ++o) biasT[o] = acc[o];
        }
      }
    }
    return;
  }
  if (bid < 245) {
    // ---- G: thread-per-(h,x,y); full dw in LDS
    float* dws = (float*)smem;  // 2400 floats
    const float4* dwf4 = reinterpret_cast<const float4*>(dw);
    float4* lds4 = reinterpret_cast<float4*>(dws);
    for (int j = tid; j < 600; j += 256) lds4[j] = dwf4[j];
    __syncthreads();
    int t = (bid - 213) * 256 + tid;
    if (t < 8000) {
      int h = t / 1600, r = t % 1600, x = r / 40, y = r % 40;
      const float* Ub = U + ((h * 40) * 40 + x) * 40 + y;
      float acc[12] = {};
      #pragma unroll 4
      for (int d = 0; d < 40; ++d) {
        float uv = Ub[d * 1600];
        #pragma unroll
        for (int o = 0; o < 12; ++o) acc[o] += dws[o * 200 + h * 40 + d] * uv;
      }
      #pragma unroll
      for (int o = 0; o < 12; ++o)
        Gp[(h * 480 + o * 40 + y) * 64 + x] = f2h(acc[o]);
    }
    return;
  }
  if (bid < 335) {
    // ---- E: wave per (o,p)
    int e = (bid - 245) * 4 + wid;   // 0..359
    int o = e / 30, p = e % 30;
    float sev[25];
    #pragma unroll
    for (int s = 0; s < 25; ++s) sev[s] = se[p * 25 + s];
    float v = 0.f;
    for (int kk = lane; kk < 200; kk += 64) {
      const float* wrow = W + kk * 427 + 402;
      float wse = 0.f;
      #pragma unroll
      for (int s = 0; s < 25; ++s) wse += wrow[s] * sev[s];
      v += dw[o * 200 + kk] * wse;
    }
    #pragma unroll
    for (int s = 1; s < 64; s <<= 1) v += __shfl_xor(v, s, 64);
    if (lane == 0) E[o * 30 + p] = v;
    return;
  }
  {
    // ---- pads (uint4 units)
    int p = (bid - 335) * 256 + tid;
    uint4 z = make_uint4(0u, 0u, 0u, 0u);
    if (p < 3072) {            // tail16 [200,224): col200 = 1.0h, rest 0
      int row = p / 3, j = p % 3;
      uint4 v = (j == 0) ? make_uint4(0x00003C00u, 0u, 0u, 0u) : z;
      *reinterpret_cast<uint4*>(tail16 + row * 224 + 200 + j * 8) = v;
    } else if (p < 3072 + 15360) {   // headp [40,64) per group
      int q = p - 3072;
      int row = q / 15, rem = q % 15, h = rem / 3, j = rem % 3;
      *reinterpret_cast<uint4*>(headp + row * 320 + h * 64 + 40 + j * 8) = z;
    } else if (p < 3072 + 15360 + 7200) {  // Gp [40,64)
      int q = p - 3072 - 15360;
      int row = q / 3, j = q % 3;
      *reinterpret_cast<uint4*>(Gp + row * 64 + 40 + j * 8) = z;
    } else if (p < 3072 + 15360 + 7200 + 180) {  // DWhp [40,64)
      int q = p - 3072 - 15360 - 7200;
      int ro = q / 3, j = q % 3, o = ro / 5, h = ro % 5;
      *reinterpret_cast<uint4*>(DWhp + o * 320 + h * 64 + 40 + j * 8) = z;
    }
    return;
  }
}

// ================= K3: fused P + main GEMM; 384 blocks (b,o,mt,n-half) =================
__global__ void __launch_bounds__(256) k3(
    const unsigned short* __restrict__ headp, const unsigned short* __restrict__ tail16,
    const unsigned short* __restrict__ Gp, const unsigned short* __restrict__ DWhp,
    const unsigned short* __restrict__ DWtp, const float* __restrict__ biasH,
    const float* __restrict__ biasT, const float* __restrict__ E,
    const float* __restrict__ db, float* __restrict__ out)
{
  __shared__ __align__(16) unsigned short Ps[64 * 232];   // 29696 B
  __shared__ __align__(16) unsigned short Gs[200 * 72];   // 28800 B (stride 72: 16B-aligned rows)
  __shared__ __align__(16) unsigned short DWh_s[320];
  __shared__ __align__(16) unsigned short DWt_s[224];
  int bid = blockIdx.x, tid = threadIdx.x;
  int nh = bid & 1, mt = (bid >> 1) & 3, ob = bid >> 3;
  int o = ob % 12, b = ob / 12;
  int wid = tid >> 6, lane = tid & 63, r15 = lane & 15, g8 = lane >> 4;

  // ---- coop stage: Gp[o] tile (200 rows x 64), DWh[o], DWt[o]; zero Ps pad cols
  for (int idx = tid; idx < 1600; idx += 256) {
    int row = idx >> 3, j = idx & 7;
    reinterpret_cast<uint4*>(&Gs[row * 72])[j] =
        reinterpret_cast<const uint4*>(Gp + ((row / 40) * 480 + o * 40 + (row % 40)) * 64)[j];
  }
  if (tid < 40)
    reinterpret_cast<uint4*>(DWh_s)[tid] = reinterpret_cast<const uint4*>(DWhp + o * 320)[tid];
  else if (tid >= 64 && tid < 92)
    reinterpret_cast<uint4*>(DWt_s)[tid - 64] = reinterpret_cast<const uint4*>(DWtp + o * 224)[tid - 64];
  for (int idx = tid; idx < 64 * 23; idx += 256)
    Ps[(idx / 23) * 232 + 201 + idx % 23] = 0;
  __syncthreads();

  // ---- phase A: wave wid computes P rows [wid*16, wid*16+16) (duplicated per n-half)
  {
    const unsigned short* arow = headp + (b * 256 + mt * 64 + wid * 16 + r15) * 320;
    f32x4 accA = {};
    #pragma unroll
    for (int h = 0; h < 5; ++h) {
      f32x4 accY[3] = {};
      #pragma unroll
      for (int ks = 0; ks < 2; ++ks) {
        half8 av = *reinterpret_cast<const half8*>(arow + h * 64 + ks * 32 + g8 * 8);
        #pragma unroll
        for (int yf = 0; yf < 3; ++yf) {
          int yy = yf * 16 + r15;
          int yc = yy < 40 ? yy : 39;
          half8 bv = *reinterpret_cast<const half8*>(&Gs[(h * 40 + yc) * 72 + ks * 32 + g8 * 8]);
          accY[yf] = mfma16(av, bv, accY[yf]);
        }
        half8 bA = *reinterpret_cast<const half8*>(&DWh_s[h * 64 + ks * 32 + g8 * 8]);
        accA = mfma16(av, bA, accA);
      }
      #pragma unroll
      for (int yf = 0; yf < 3; ++yf) {
        int yy = yf * 16 + r15;
        if (yy < 40) {
          int c = h * 40 + yy;
          float dwt = h2f(DWt_s[c]);   // Bt fold
          #pragma unroll
          for (int q = 0; q < 4; ++q)
            Ps[(wid * 16 + g8 * 4 + q) * 232 + c] = f2h(accY[yf][q] + dwt);
        }
      }
    }
    if (r15 == 0) {
      float cst = biasH[o] + biasT[o] + db[o];
      #pragma unroll
      for (int q = 0; q < 4; ++q)
        Ps[(wid * 16 + g8 * 4 + q) * 232 + 200] = f2h(accA[q] + cst);  // A fold
    }
  }
  __syncthreads();

  // ---- phase B: wave wid owns output cols [nh*128 + wid*32, +32)
  const uint4* bptr[2];
  #pragma unroll
  for (int hf = 0; hf < 2; ++hf)
    bptr[hf] = reinterpret_cast<const uint4*>(
        tail16 + (b * 256 + nh * 128 + wid * 32 + hf * 16 + r15) * 224);

  f32x4 acc[4][2] = {};
  #pragma unroll
  for (int ks = 0; ks < 7; ++ks) {
    int idx = ks * 4 + g8;
    half8 a[4], bb[2];
    #pragma unroll
    for (int g = 0; g < 4; ++g)
      a[g] = *reinterpret_cast<const half8*>(&Ps[(g * 16 + r15) * 232 + ks * 32 + g8 * 8]);
    #pragma unroll
    for (int hf = 0; hf < 2; ++hf) bb[hf] = __builtin_bit_cast(half8, bptr[hf][idx]);
    #pragma unroll
    for (int g = 0; g < 4; ++g) {
      #pragma unroll
      for (int hf = 0; hf < 2; ++hf)
        acc[g][hf] = mfma16(a[g], bb[hf], acc[g][hf]);
    }
  }
  const float* Erow = E + o * 30;
  #pragma unroll
  for (int g = 0; g < 4; ++g) {
    #pragma unroll
    for (int q = 0; q < 4; ++q) {
      int m = mt * 64 + g * 16 + g8 * 4 + q;
      #pragma unroll
      for (int hf = 0; hf < 2; ++hf) {
        int n = nh * 128 + wid * 32 + hf * 16 + r15;
        int dpos = n - m;
        dpos = (dpos < -15) ? -15 : (dpos > 14 ? 14 : dpos);
        out[((b * 12 + o) * 256 + m) * 256 + n] = acc[g][hf][q] + Erow[dpos + 15];
      }
    }
  }
}

extern "C" void kernel_launch(void* const* d_in, const int* in_sizes, int n_in,
                              void* d_out, int out_size, void* d_ws, size_t ws_size,
                              hipStream_t stream) {
  (void)in_sizes; (void)n_in; (void)out_size; (void)ws_size;
  const float* wr = (const float*)d_in[0];
  const float* hw = (const float*)d_in[4];
  const float* hb = (const float*)d_in[5];
  const float* tw = (const float*)d_in[6];
  const float* tb = (const float*)d_in[7];
  const float* U  = (const float*)d_in[8];
  const float* se = (const float*)d_in[9];
  const float* W  = (const float*)d_in[10];
  const float* dw = (const float*)d_in[11];
  const float* db = (const float*)d_in[12];

  char* ws = (char*)d_ws;
  unsigned short* headp  = (unsigned short*)(ws + 0);        //   655,360  [1024][320]
  unsigned short* tail16 = (unsigned short*)(ws + 655360);   //   458,752  [1024][224]
  unsigned short* Gp     = (unsigned short*)(ws + 1114112);  //   307,200  [2400][64]
  unsigned short* DWhp   = (unsigned short*)(ws + 1421312);  //     7,680
  unsigned short* DWtp   = (unsigned short*)(ws + 1428992);  //     5,376
  float* biasH           = (float*)(ws + 1434368);           //        64
  float* biasT           = (float*)(ws + 1434432);           //        64
  float* E_ws            = (float*)(ws + 1434496);           //     1,440  -> end ~1.44 MB

  k1<<<436, 256, 0, stream>>>(wr, hw, tw, hb, tb, U, W, dw, se,
                              headp, tail16, DWhp, DWtp, biasH, biasT, E_ws, Gp);
  k3<<<384, 256, 0, stream>>>(headp, tail16, Gp, DWhp, DWtp, biasH, biasT,
                              E_ws, db, (float*)d_out);
}